// Round 16
// baseline (101.466 us; speedup 1.0000x reference)
//
#include <hip/hip_runtime.h>
#include <hip/hip_bf16.h>

#define N 4096
#define IND 256
#define OUTD 128
#define NEGV -9000000000000000.0f

typedef __attribute__((ext_vector_type(8))) short bf16x8;
typedef __attribute__((ext_vector_type(4))) float f32x4;

static __device__ __forceinline__ unsigned short f2bf(float x) {
    unsigned int u = __float_as_uint(x);
    u = (u + 0x7FFFu + ((u >> 16) & 1u)) >> 16;   // round-nearest-even
    return (unsigned short)u;
}

// ---------------- Kernel A: wh = lstm_out @ W  (4096x256 @ 256x128) ----------------
__global__ __launch_bounds__(256) void wh_kernel(const float* __restrict__ x,
                                                 const float* __restrict__ W,
                                                 float* __restrict__ wh) {
    __shared__ float xs[8][IND];
    const int t = threadIdx.x;
    const int i0 = blockIdx.x * 8;
    const float4* src = (const float4*)(x + (size_t)i0 * IND);
    float4* dst = (float4*)&xs[0][0];
    dst[t] = src[t];
    dst[t + 256] = src[t + 256];
    __syncthreads();
    const int c = t & 127;
    const int rbase = (t >> 7) * 4;
    float acc[4] = {0.f, 0.f, 0.f, 0.f};
    #pragma unroll 4
    for (int k = 0; k < IND; k += 4) {
        const float w0 = W[(k + 0) * OUTD + c];
        const float w1 = W[(k + 1) * OUTD + c];
        const float w2 = W[(k + 2) * OUTD + c];
        const float w3 = W[(k + 3) * OUTD + c];
        #pragma unroll
        for (int r = 0; r < 4; ++r) {
            const float4 xv = *(const float4*)&xs[rbase + r][k];
            acc[r] = fmaf(xv.x, w0, acc[r]);
            acc[r] = fmaf(xv.y, w1, acc[r]);
            acc[r] = fmaf(xv.z, w2, acc[r]);
            acc[r] = fmaf(xv.w, w3, acc[r]);
        }
    }
    #pragma unroll
    for (int r = 0; r < 4; ++r)
        wh[(size_t)(i0 + rbase + r) * OUTD + c] = acc[r];
}

// ---------------- Kernel A2: s_i = wh @ a_i, s_j = wh @ a_j ----------------
__global__ __launch_bounds__(128) void sij_kernel(const float* __restrict__ wh,
                                                  const float* __restrict__ a,
                                                  float* __restrict__ s_i,
                                                  float* __restrict__ s_j) {
    const int i = blockIdx.x;
    const int c = threadIdx.x;
    float v = wh[(size_t)i * OUTD + c];
    float p = v * a[c];              // a_i = a[0:128]
    float q = v * a[OUTD + 5 + c];   // a_j = a[133:261]
    #pragma unroll
    for (int off = 32; off >= 1; off >>= 1) {
        p += __shfl_down(p, off);
        q += __shfl_down(q, off);
    }
    __shared__ float tmp[4];
    if ((c & 63) == 0) { tmp[c >> 6] = p; tmp[2 + (c >> 6)] = q; }
    __syncthreads();
    if (c == 0) { s_i[i] = tmp[0] + tmp[1]; s_j[i] = tmp[2] + tmp[3]; }
}

// ---------------- Kernel A3: whT[c][j] = bf16(wh[j][c])  (B-operand layout) ----------------
__global__ __launch_bounds__(256) void whT_kernel(const float* __restrict__ wh,
                                                  unsigned short* __restrict__ whT) {
    __shared__ float ls[64][130];
    const int t = threadIdx.x;
    const int j0 = blockIdx.x * 64;
    #pragma unroll
    for (int k = 0; k < 32; ++k) {
        const int idx = k * 256 + t;
        const int j = idx >> 7;
        const int c = idx & 127;
        ls[j][c] = wh[(size_t)(j0 + j) * OUTD + c];
    }
    __syncthreads();
    #pragma unroll
    for (int k = 0; k < 32; ++k) {
        const int idx = k * 256 + t;
        const int c = idx >> 6;
        const int j = idx & 63;
        whT[(size_t)c * N + j0 + j] = f2bf(ls[j][c]);
    }
}

// ---------------- Kernel B: flash GAT with MFMA PV, 3 blocks/CU ----------------
// ROUND-16: r15 at 2 blocks/CU had HBM duty ~73% (each block exposes only 20 KB
// per ~2750-cyc iteration vs ~2000-cyc service). Compute is now nearly free
// (MFMA), so this is a genuine more-streams regime (r11's "more blocks" null
// was compute-bound — doesn't transfer). Changes: E[3]->E[2] (LDS 64.6->44.6 KB
// => 3 blocks/CU) and NCH=4 (grid 1024 so the 3rd slot fills). Pipeline is now
// 1-deep: counted vmcnt(5)+barrier before scores retires exactly stage(st)
// (FIFO: sj_nx(st-1)[1] + stage(st)[5] are the oldest 6; B(st)[4]+sj_nx(st)[1]
// stay in flight). Per iter:
//   [A] B-frags(st)+sj(st+1) -> regs; sched_barrier
//   [W] vmcnt(5) + s_barrier        (stage(st) LDS writes visible)
//   [C] scores(st) E[b]->P[pb] bf16 (p=exp(s) direct, r13-validated)
//   [D] STAGE(st+1) -> E[b^1]       (in flight through MFMA + next [A])
//   [E] lgkmcnt(0) + s_barrier      (P visible; stage NOT drained)
//   [F] MFMA x4 (A from P b128, B from regs)
// P double-buffered => no third barrier (readers of P[pb^1] at [F](st-1) are
// separated from writer [C](st+1) by the [W]/[E] barriers of iter st).
// VGPR ~90 under (256,1) cap 256 (model confirmed r8).
#define BI 16
#define BJ 64
#define NCH 4
#define CHJ (N / NCH)          // 1024
#define NSUB (CHJ / BJ)        // 16
#define PPAD 72                // P row stride in bf16 (144 B)
#define EFLOATS (BI * BJ * 5)  // 5120 floats = 20 KB per buffer

__device__ __forceinline__ void gload_lds16(const void* g, void* l) {
    __builtin_amdgcn_global_load_lds(
        (const __attribute__((address_space(1))) unsigned int*)(g),
        (__attribute__((address_space(3))) unsigned int*)(l),
        16, 0, 0);
}

__global__ __launch_bounds__(256, 1) void gat_mfma(const float* __restrict__ edges,
                                                   const unsigned short* __restrict__ whT,
                                                   const float* __restrict__ s_iv,
                                                   const float* __restrict__ s_jv,
                                                   const float* __restrict__ a,
                                                   float* __restrict__ part,
                                                   float* __restrict__ lout) {
    __shared__ float E[2][EFLOATS];              // 40 KB
    __shared__ unsigned short P[2][BI * PPAD];   // 4.6 KB

    const int t = threadIdx.x;
    const int ib = blockIdx.x & 255;
    const int ch = blockIdx.x >> 8;
    const int i0 = ib * BI;
    const int jbase = ch * CHJ;
    const int w = t >> 6;
    const int s = t & 63;
    const int lhi = s >> 4;
    const int llo = s & 15;

    const float ae0 = a[OUTD + 0], ae1 = a[OUTD + 1], ae2 = a[OUTD + 2],
                ae3 = a[OUTD + 3], ae4 = a[OUTD + 4];
    float si[4];
    #pragma unroll
    for (int rr = 0; rr < 4; ++rr) si[rr] = s_iv[i0 + 4 * w + rr];

    // Stage sources: float4 f = k*256+t of the 1280-float4 (16x64x5) tile.
    const char* g0; const char* g1; const char* g2; const char* g3; const char* g4;
    {
        const char* eb = (const char*)edges + (size_t)jbase * 20;
        #define MKG(K, VAR)                                                    \
        {   const int f = K * 256 + t;                                         \
            const int row = f / 80;                                            \
            const int rem = f - row * 80;                                      \
            VAR = eb + (size_t)(i0 + row) * (N * 20) + (size_t)rem * 16; }
        MKG(0, g0) MKG(1, g1) MKG(2, g2) MKG(3, g3) MKG(4, g4)
        #undef MKG
    }
    #define STAGE(BB, ST)                                                      \
    {   const size_t jo = (size_t)(ST) * (BJ * 20);                            \
        gload_lds16(g0 + jo, &E[BB][(0 * 256 + t) * 4]);                       \
        gload_lds16(g1 + jo, &E[BB][(1 * 256 + t) * 4]);                       \
        gload_lds16(g2 + jo, &E[BB][(2 * 256 + t) * 4]);                       \
        gload_lds16(g3 + jo, &E[BB][(3 * 256 + t) * 4]);                       \
        gload_lds16(g4 + jo, &E[BB][(4 * 256 + t) * 4]); }

    f32x4 acc0 = {0.f, 0.f, 0.f, 0.f};
    f32x4 acc1 = {0.f, 0.f, 0.f, 0.f};
    float lac[4] = {0.f, 0.f, 0.f, 0.f};

    const unsigned short* wt0 = whT + (size_t)(w * 32 + llo) * N;
    const unsigned short* wt1 = wt0 + (size_t)16 * N;

    // ---- prologue: sj(0) then stage(0); loop's [W] does the wait ----
    float sj = s_jv[jbase + s];
    STAGE(0, 0)

    for (int st = 0; st < NSUB; ++st) {
        const int b = st & 1;
        const int pb = st & 1;
        const int jb = jbase + st * BJ;

        // ---- [A] B-fragments(st) + sj(st+1) -> regs ----
        const int kof = jb + lhi * 8;
        const bf16x8 B00 = *(const bf16x8*)(wt0 + kof);
        const bf16x8 B01 = *(const bf16x8*)(wt0 + kof + 32);
        const bf16x8 B10 = *(const bf16x8*)(wt1 + kof);
        const bf16x8 B11 = *(const bf16x8*)(wt1 + kof + 32);
        float sj_nx = 0.f;
        if (st + 1 < NSUB) sj_nx = s_jv[jb + BJ + s];
        __builtin_amdgcn_sched_barrier(0);

        // ---- [W] counted wait: retire stage(st) (oldest 6 = sj_prev + stage);
        //      B(st)+sj_nx stay in flight. Barrier publishes stage LDS writes.
        asm volatile("s_waitcnt vmcnt(5)" ::: "memory");
        __builtin_amdgcn_s_barrier();
        __builtin_amdgcn_sched_barrier(0);

        // ---- [C] scores(st): p = exp(s) direct, bf16 -> P ----
        {
            const float* Eb = &E[b][0];
            #pragma unroll
            for (int rr = 0; rr < 4; ++rr) {
                const int row = 4 * w + rr;
                const int e = row * 320 + s * 5;
                float d = Eb[e + 4] * ae4;
                d = fmaf(Eb[e + 0], ae0, d);
                d = fmaf(Eb[e + 1], ae1, d);
                d = fmaf(Eb[e + 2], ae2, d);
                d = fmaf(Eb[e + 3], ae3, d);
                float v = si[rr] + d + sj;
                v = fmaxf(v, 0.2f * v);             // leaky relu before mask
                if (jb + s == i0 + row) v = NEGV;   // diag -> exp -> 0
                const float p = __expf(v);
                lac[rr] += p;
                P[pb][row * PPAD + s] = f2bf(p);
            }
        }

        // ---- [D] stage st+1 into E[b^1] ----
        if (st + 1 < NSUB) {
            STAGE(b ^ 1, st + 1)
        }

        // ---- [E] LDS-only barrier: P visible; stage stays in flight ----
        asm volatile("s_waitcnt lgkmcnt(0)" ::: "memory");
        __builtin_amdgcn_s_barrier();
        asm volatile("" ::: "memory");

        // ---- [F] MFMA PV ----
        {
            const unsigned short* Pb = &P[pb][0];
            const bf16x8 A0 = *(const bf16x8*)(Pb + llo * PPAD + lhi * 8);
            const bf16x8 A1 = *(const bf16x8*)(Pb + llo * PPAD + 32 + lhi * 8);
            acc0 = __builtin_amdgcn_mfma_f32_16x16x32_bf16(A0, B00, acc0, 0, 0, 0);
            acc1 = __builtin_amdgcn_mfma_f32_16x16x32_bf16(A0, B10, acc1, 0, 0, 0);
            acc0 = __builtin_amdgcn_mfma_f32_16x16x32_bf16(A1, B01, acc0, 0, 0, 0);
            acc1 = __builtin_amdgcn_mfma_f32_16x16x32_bf16(A1, B11, acc1, 0, 0, 0);
        }

        sj = sj_nx;
    }

    // ---- epilogue: reduce l once; write raw partials (merge normalizes) ----
    #pragma unroll
    for (int rr = 0; rr < 4; ++rr) {
        #pragma unroll
        for (int off = 32; off >= 1; off >>= 1)
            lac[rr] += __shfl_xor(lac[rr], off);
    }
    if (s == 0) {
        #pragma unroll
        for (int rr = 0; rr < 4; ++rr)
            lout[(size_t)ch * N + i0 + 4 * w + rr] = lac[rr];
    }
    #pragma unroll
    for (int reg = 0; reg < 4; ++reg) {
        const int row = lhi * 4 + reg;          // D row = (lane>>4)*4 + reg
        float* pr = part + ((size_t)ch * N + (i0 + row)) * OUTD + w * 32 + llo;
        pr[0]  = acc0[reg];
        pr[16] = acc1[reg];
    }
}

// ---------------- Kernel C: merge the 4 chunk partials ----------------
__global__ __launch_bounds__(256) void gat_merge(const float* __restrict__ part,
                                                 const float* __restrict__ lout,
                                                 float* __restrict__ out) {
    const int idx = blockIdx.x * 256 + threadIdx.x;   // over N*OUTD
    const int i = idx >> 7;
    const float L = lout[i] + lout[N + i] + lout[2 * N + i] + lout[3 * N + i];
    const float v = part[idx] + part[(size_t)N * OUTD + idx]
                  + part[2 * (size_t)N * OUTD + idx]
                  + part[3 * (size_t)N * OUTD + idx];
    out[idx] = v / L;
}

extern "C" void kernel_launch(void* const* d_in, const int* in_sizes, int n_in,
                              void* d_out, int out_size, void* d_ws, size_t ws_size,
                              hipStream_t stream) {
    // inputs: 0=ids(int, unused), 1=lstm_out, 2=edges_list, 3=W, 4=a, 5=first(unused)
    const float* lstm_out = (const float*)d_in[1];
    const float* edges    = (const float*)d_in[2];
    const float* W        = (const float*)d_in[3];
    const float* a        = (const float*)d_in[4];
    float* out = (float*)d_out;

    float* wh   = (float*)d_ws;                        // 4096*128 f32
    float* s_i  = wh + (size_t)N * OUTD;               // 4096
    float* s_j  = s_i + N;                             // 4096
    float* lout = s_j + N;                             // 4*4096
    float* part = lout + (size_t)NCH * N;              // 4*4096*128 f32 (8 MB)
    unsigned short* whT = (unsigned short*)(part + (size_t)NCH * N * OUTD); // 1 MB

    wh_kernel<<<N / 8, 256, 0, stream>>>(lstm_out, W, wh);
    sij_kernel<<<N, 128, 0, stream>>>(wh, a, s_i, s_j);
    whT_kernel<<<N / 64, 256, 0, stream>>>(wh, whT);
    gat_mfma<<<256 * NCH, 256, 0, stream>>>(edges, whT, s_i, s_j, a, part, lout);
    gat_merge<<<(N * OUTD) / 256, 256, 0, stream>>>(part, lout, out);
}

// Round 17
// 99.307 us; speedup vs baseline: 1.0217x; 1.0217x over previous
//
#include <hip/hip_runtime.h>
#include <hip/hip_bf16.h>

#define N 4096
#define IND 256
#define OUTD 128
#define NEGV -9000000000000000.0f

typedef __attribute__((ext_vector_type(8))) short bf16x8;
typedef __attribute__((ext_vector_type(4))) float f32x4;

static __device__ __forceinline__ unsigned short f2bf(float x) {
    unsigned int u = __float_as_uint(x);
    u = (u + 0x7FFFu + ((u >> 16) & 1u)) >> 16;   // round-nearest-even
    return (unsigned short)u;
}

// ---------------- Kernel A: wh = lstm_out @ W  (4096x256 @ 256x128) ----------------
__global__ __launch_bounds__(256) void wh_kernel(const float* __restrict__ x,
                                                 const float* __restrict__ W,
                                                 float* __restrict__ wh) {
    __shared__ float xs[8][IND];
    const int t = threadIdx.x;
    const int i0 = blockIdx.x * 8;
    const float4* src = (const float4*)(x + (size_t)i0 * IND);
    float4* dst = (float4*)&xs[0][0];
    dst[t] = src[t];
    dst[t + 256] = src[t + 256];
    __syncthreads();
    const int c = t & 127;
    const int rbase = (t >> 7) * 4;
    float acc[4] = {0.f, 0.f, 0.f, 0.f};
    #pragma unroll 4
    for (int k = 0; k < IND; k += 4) {
        const float w0 = W[(k + 0) * OUTD + c];
        const float w1 = W[(k + 1) * OUTD + c];
        const float w2 = W[(k + 2) * OUTD + c];
        const float w3 = W[(k + 3) * OUTD + c];
        #pragma unroll
        for (int r = 0; r < 4; ++r) {
            const float4 xv = *(const float4*)&xs[rbase + r][k];
            acc[r] = fmaf(xv.x, w0, acc[r]);
            acc[r] = fmaf(xv.y, w1, acc[r]);
            acc[r] = fmaf(xv.z, w2, acc[r]);
            acc[r] = fmaf(xv.w, w3, acc[r]);
        }
    }
    #pragma unroll
    for (int r = 0; r < 4; ++r)
        wh[(size_t)(i0 + rbase + r) * OUTD + c] = acc[r];
}

// ---------------- Kernel A2: s_i = wh @ a_i, s_j = wh @ a_j ----------------
__global__ __launch_bounds__(128) void sij_kernel(const float* __restrict__ wh,
                                                  const float* __restrict__ a,
                                                  float* __restrict__ s_i,
                                                  float* __restrict__ s_j) {
    const int i = blockIdx.x;
    const int c = threadIdx.x;
    float v = wh[(size_t)i * OUTD + c];
    float p = v * a[c];              // a_i = a[0:128]
    float q = v * a[OUTD + 5 + c];   // a_j = a[133:261]
    #pragma unroll
    for (int off = 32; off >= 1; off >>= 1) {
        p += __shfl_down(p, off);
        q += __shfl_down(q, off);
    }
    __shared__ float tmp[4];
    if ((c & 63) == 0) { tmp[c >> 6] = p; tmp[2 + (c >> 6)] = q; }
    __syncthreads();
    if (c == 0) { s_i[i] = tmp[0] + tmp[1]; s_j[i] = tmp[2] + tmp[3]; }
}

// ---------------- Kernel A3: whT[c][j] = bf16(wh[j][c])  (B-operand layout) ----------------
__global__ __launch_bounds__(256) void whT_kernel(const float* __restrict__ wh,
                                                  unsigned short* __restrict__ whT) {
    __shared__ float ls[64][130];
    const int t = threadIdx.x;
    const int j0 = blockIdx.x * 64;
    #pragma unroll
    for (int k = 0; k < 32; ++k) {
        const int idx = k * 256 + t;
        const int j = idx >> 7;
        const int c = idx & 127;
        ls[j][c] = wh[(size_t)(j0 + j) * OUTD + c];
    }
    __syncthreads();
    #pragma unroll
    for (int k = 0; k < 32; ++k) {
        const int idx = k * 256 + t;
        const int c = idx >> 6;
        const int j = idx & 63;
        whT[(size_t)c * N + j0 + j] = f2bf(ls[j][c]);
    }
}

// ---------------- Kernel B: MFMA GAT, edges DIRECT global->registers ----------------
// ROUND-17: r16's fallback fired (3 blocks/CU via 1-deep pipeline lost to r15's
// 2-deep at 2 blocks). r15's remaining overhead (~2100 cyc/slot over the 3900
// HBM service) is the E-staging machinery itself: edges are SINGLE-USE, yet we
// paid global_load_lds + 20 LDS reads/lane + an extra barrier to bounce them
// through LDS (Common-mistake #7). The scores access pattern (lane s -> 20
// contiguous bytes at j=jb+s) is wave-contiguous (64x20B = 1280B span), so
// direct global->reg loads coalesce via L1 line reuse. Changes vs r15:
//   - E[] deleted (LDS now just P[2] = 4.6 KB); VGPR-bound occupancy 3-4
//     blocks/CU (pressure ~110; r10's reg-prefetch failure was at ~200).
//   - eA/eB double-buffered edge regs (20 floats), 2x-unrolled loop (static
//     indexing, rule #20); prefetch edges(st+1) issued top of iter st.
//   - ONE lgkm-barrier per iter. Race-free: any wave at scores(st+2)->P[pb]
//     passed barrier(st+1); all waves' MFMA(st) reads of P[pb] complete before
//     they arrive there (ds_read results consumed pre-barrier in program order).
//   - NCH=4 (grid 1024) to fill the extra CU slots; merge over 4 chunks.
//   - VMEM issue order pinned B-frags -> edges -> sj (sched_barrier): scores'
//     wait on eCUR (oldest) never forces this iter's newer loads.
// VGPR-cap model (r3-r8): (256,1) -> cap 256. Spill sentinel: WRITE_SIZE.
#define BI 16
#define BJ 64
#define NCH 4
#define CHJ (N / NCH)          // 1024
#define NSUB (CHJ / BJ)        // 16
#define PPAD 72                // P row stride in bf16 (144 B)

__global__ __launch_bounds__(256, 1) void gat_reg(const float* __restrict__ edges,
                                                  const unsigned short* __restrict__ whT,
                                                  const float* __restrict__ s_iv,
                                                  const float* __restrict__ s_jv,
                                                  const float* __restrict__ a,
                                                  float* __restrict__ part,
                                                  float* __restrict__ lout) {
    __shared__ unsigned short P[2][BI * PPAD];   // 4.6 KB total LDS

    const int t = threadIdx.x;
    const int ib = blockIdx.x & 255;
    const int ch = blockIdx.x >> 8;
    const int i0 = ib * BI;
    const int jbase = ch * CHJ;
    const int w = t >> 6;
    const int s = t & 63;
    const int lhi = s >> 4;
    const int llo = s & 15;

    const float ae0 = a[OUTD + 0], ae1 = a[OUTD + 1], ae2 = a[OUTD + 2],
                ae3 = a[OUTD + 3], ae4 = a[OUTD + 4];
    float si[4];
    #pragma unroll
    for (int rr = 0; rr < 4; ++rr) si[rr] = s_iv[i0 + 4 * w + rr];

    // per-lane edge row pointers (row = i0+4w+r, col = jbase+s)
    const float* er0 = edges + ((size_t)(i0 + 4 * w + 0) * N + jbase + s) * 5;
    const float* er1 = edges + ((size_t)(i0 + 4 * w + 1) * N + jbase + s) * 5;
    const float* er2 = edges + ((size_t)(i0 + 4 * w + 2) * N + jbase + s) * 5;
    const float* er3 = edges + ((size_t)(i0 + 4 * w + 3) * N + jbase + s) * 5;

    const unsigned short* wt0 = whT + (size_t)(w * 32 + llo) * N;
    const unsigned short* wt1 = wt0 + (size_t)16 * N;

    f32x4 acc0 = {0.f, 0.f, 0.f, 0.f};
    f32x4 acc1 = {0.f, 0.f, 0.f, 0.f};
    float lac[4] = {0.f, 0.f, 0.f, 0.f};

    float eA[4][5], eB[4][5];
    float sj = s_jv[jbase + s];
    // prologue: edges(0) -> eA (first use auto-waits)
    #pragma unroll
    for (int k = 0; k < 5; ++k) {
        eA[0][k] = er0[k];
        eA[1][k] = er1[k];
        eA[2][k] = er2[k];
        eA[3][k] = er3[k];
    }

    // ITER(ST): consume EC regs; prefetch edges(ST+1) into EN.
    #define ITER(ST, EC, EN)                                                   \
    {                                                                          \
        const int jb = jbase + (ST) * BJ;                                      \
        const int pb = (ST) & 1;                                               \
        /* [A] B-frags FIRST (so MFMA's wait never forces the edge loads) */   \
        const int kof = jb + lhi * 8;                                          \
        const bf16x8 B00 = *(const bf16x8*)(wt0 + kof);                        \
        const bf16x8 B01 = *(const bf16x8*)(wt0 + kof + 32);                   \
        const bf16x8 B10 = *(const bf16x8*)(wt1 + kof);                        \
        const bf16x8 B11 = *(const bf16x8*)(wt1 + kof + 32);                   \
        /* edges(ST+1) -> EN, then sj(ST+1) */                                 \
        float sj_nx = 0.f;                                                     \
        if ((ST) + 1 < NSUB) {                                                 \
            const int off = ((ST) + 1) * (BJ * 5);                             \
            _Pragma("unroll")                                                  \
            for (int k = 0; k < 5; ++k) {                                      \
                EN[0][k] = er0[off + k];                                       \
                EN[1][k] = er1[off + k];                                       \
                EN[2][k] = er2[off + k];                                       \
                EN[3][k] = er3[off + k];                                       \
            }                                                                  \
            sj_nx = s_jv[jb + BJ + s];                                         \
        }                                                                      \
        __builtin_amdgcn_sched_barrier(0);                                     \
        /* [C] scores(ST) from EC regs -> P[pb] bf16 (p=exp(s) direct) */      \
        _Pragma("unroll")                                                      \
        for (int rr = 0; rr < 4; ++rr) {                                       \
            const int row = 4 * w + rr;                                        \
            float d = EC[rr][4] * ae4;                                         \
            d = fmaf(EC[rr][0], ae0, d);                                       \
            d = fmaf(EC[rr][1], ae1, d);                                       \
            d = fmaf(EC[rr][2], ae2, d);                                       \
            d = fmaf(EC[rr][3], ae3, d);                                       \
            float v = si[rr] + d + sj;                                         \
            v = fmaxf(v, 0.2f * v);          /* leaky relu before mask */      \
            if (jb + s == i0 + row) v = NEGV;                                  \
            const float p = __expf(v);                                         \
            lac[rr] += p;                                                      \
            P[pb][row * PPAD + s] = f2bf(p);                                   \
        }                                                                      \
        /* [E] single barrier: P writes visible; edge loads stay in flight */  \
        asm volatile("s_waitcnt lgkmcnt(0)" ::: "memory");                     \
        __builtin_amdgcn_s_barrier();                                          \
        asm volatile("" ::: "memory");                                         \
        /* [F] MFMA PV */                                                      \
        {                                                                      \
            const unsigned short* Pb = &P[pb][0];                              \
            const bf16x8 A0 = *(const bf16x8*)(Pb + llo * PPAD + lhi * 8);     \
            const bf16x8 A1 = *(const bf16x8*)(Pb + llo * PPAD + 32 + lhi * 8);\
            acc0 = __builtin_amdgcn_mfma_f32_16x16x32_bf16(A0, B00, acc0, 0, 0, 0); \
            acc1 = __builtin_amdgcn_mfma_f32_16x16x32_bf16(A0, B10, acc1, 0, 0, 0); \
            acc0 = __builtin_amdgcn_mfma_f32_16x16x32_bf16(A1, B01, acc0, 0, 0, 0); \
            acc1 = __builtin_amdgcn_mfma_f32_16x16x32_bf16(A1, B11, acc1, 0, 0, 0); \
        }                                                                      \
        sj = sj_nx;                                                            \
    }

    for (int st = 0; st < NSUB; st += 2) {
        ITER(st, eA, eB)
        ITER(st + 1, eB, eA)
    }
    #undef ITER

    // ---- epilogue: reduce l once; write raw partials (merge normalizes) ----
    #pragma unroll
    for (int rr = 0; rr < 4; ++rr) {
        #pragma unroll
        for (int off = 32; off >= 1; off >>= 1)
            lac[rr] += __shfl_xor(lac[rr], off);
    }
    if (s == 0) {
        #pragma unroll
        for (int rr = 0; rr < 4; ++rr)
            lout[(size_t)ch * N + i0 + 4 * w + rr] = lac[rr];
    }
    #pragma unroll
    for (int reg = 0; reg < 4; ++reg) {
        const int row = lhi * 4 + reg;          // D row = (lane>>4)*4 + reg
        float* pr = part + ((size_t)ch * N + (i0 + row)) * OUTD + w * 32 + llo;
        pr[0]  = acc0[reg];
        pr[16] = acc1[reg];
    }
}

// ---------------- Kernel C: merge the 4 chunk partials ----------------
__global__ __launch_bounds__(256) void gat_merge(const float* __restrict__ part,
                                                 const float* __restrict__ lout,
                                                 float* __restrict__ out) {
    const int idx = blockIdx.x * 256 + threadIdx.x;   // over N*OUTD
    const int i = idx >> 7;
    const float L = lout[i] + lout[N + i] + lout[2 * N + i] + lout[3 * N + i];
    const float v = part[idx] + part[(size_t)N * OUTD + idx]
                  + part[2 * (size_t)N * OUTD + idx]
                  + part[3 * (size_t)N * OUTD + idx];
    out[idx] = v / L;
}

extern "C" void kernel_launch(void* const* d_in, const int* in_sizes, int n_in,
                              void* d_out, int out_size, void* d_ws, size_t ws_size,
                              hipStream_t stream) {
    // inputs: 0=ids(int, unused), 1=lstm_out, 2=edges_list, 3=W, 4=a, 5=first(unused)
    const float* lstm_out = (const float*)d_in[1];
    const float* edges    = (const float*)d_in[2];
    const float* W        = (const float*)d_in[3];
    const float* a        = (const float*)d_in[4];
    float* out = (float*)d_out;

    float* wh   = (float*)d_ws;                        // 4096*128 f32
    float* s_i  = wh + (size_t)N * OUTD;               // 4096
    float* s_j  = s_i + N;                             // 4096
    float* lout = s_j + N;                             // 4*4096
    float* part = lout + (size_t)NCH * N;              // 4*4096*128 f32 (8 MB)
    unsigned short* whT = (unsigned short*)(part + (size_t)NCH * N * OUTD); // 1 MB

    wh_kernel<<<N / 8, 256, 0, stream>>>(lstm_out, W, wh);
    sij_kernel<<<N, 128, 0, stream>>>(wh, a, s_i, s_j);
    whT_kernel<<<N / 64, 256, 0, stream>>>(wh, whT);
    gat_reg<<<256 * NCH, 256, 0, stream>>>(edges, whT, s_i, s_j, a, part, lout);
    gat_merge<<<(N * OUTD) / 256, 256, 0, stream>>>(part, lout, out);
}

// Round 18
// 90.927 us; speedup vs baseline: 1.1159x; 1.0922x over previous
//
#include <hip/hip_runtime.h>
#include <hip/hip_bf16.h>

#define N 4096
#define IND 256
#define OUTD 128
#define NEGV -9000000000000000.0f

typedef __attribute__((ext_vector_type(8))) short bf16x8;
typedef __attribute__((ext_vector_type(4))) float f32x4;

static __device__ __forceinline__ unsigned short f2bf(float x) {
    unsigned int u = __float_as_uint(x);
    u = (u + 0x7FFFu + ((u >> 16) & 1u)) >> 16;   // round-nearest-even
    return (unsigned short)u;
}

// ---------------- Kernel A: wh = lstm_out @ W  (4096x256 @ 256x128) ----------------
__global__ __launch_bounds__(256) void wh_kernel(const float* __restrict__ x,
                                                 const float* __restrict__ W,
                                                 float* __restrict__ wh) {
    __shared__ float xs[8][IND];
    const int t = threadIdx.x;
    const int i0 = blockIdx.x * 8;
    const float4* src = (const float4*)(x + (size_t)i0 * IND);
    float4* dst = (float4*)&xs[0][0];
    dst[t] = src[t];
    dst[t + 256] = src[t + 256];
    __syncthreads();
    const int c = t & 127;
    const int rbase = (t >> 7) * 4;
    float acc[4] = {0.f, 0.f, 0.f, 0.f};
    #pragma unroll 4
    for (int k = 0; k < IND; k += 4) {
        const float w0 = W[(k + 0) * OUTD + c];
        const float w1 = W[(k + 1) * OUTD + c];
        const float w2 = W[(k + 2) * OUTD + c];
        const float w3 = W[(k + 3) * OUTD + c];
        #pragma unroll
        for (int r = 0; r < 4; ++r) {
            const float4 xv = *(const float4*)&xs[rbase + r][k];
            acc[r] = fmaf(xv.x, w0, acc[r]);
            acc[r] = fmaf(xv.y, w1, acc[r]);
            acc[r] = fmaf(xv.z, w2, acc[r]);
            acc[r] = fmaf(xv.w, w3, acc[r]);
        }
    }
    #pragma unroll
    for (int r = 0; r < 4; ++r)
        wh[(size_t)(i0 + rbase + r) * OUTD + c] = acc[r];
}

// ---------------- Kernel A2: s_i = wh @ a_i, s_j = wh @ a_j ----------------
__global__ __launch_bounds__(128) void sij_kernel(const float* __restrict__ wh,
                                                  const float* __restrict__ a,
                                                  float* __restrict__ s_i,
                                                  float* __restrict__ s_j) {
    const int i = blockIdx.x;
    const int c = threadIdx.x;
    float v = wh[(size_t)i * OUTD + c];
    float p = v * a[c];              // a_i = a[0:128]
    float q = v * a[OUTD + 5 + c];   // a_j = a[133:261]
    #pragma unroll
    for (int off = 32; off >= 1; off >>= 1) {
        p += __shfl_down(p, off);
        q += __shfl_down(q, off);
    }
    __shared__ float tmp[4];
    if ((c & 63) == 0) { tmp[c >> 6] = p; tmp[2 + (c >> 6)] = q; }
    __syncthreads();
    if (c == 0) { s_i[i] = tmp[0] + tmp[1]; s_j[i] = tmp[2] + tmp[3]; }
}

// ---------------- Kernel A3: whT[c][j] = bf16(wh[j][c])  (B-operand layout) ----------------
// 64 blocks x 256 thr; LDS transpose; coalesced read AND write (wave-contiguous).
__global__ __launch_bounds__(256) void whT_kernel(const float* __restrict__ wh,
                                                  unsigned short* __restrict__ whT) {
    __shared__ float ls[64][130];   // +2 pad: phase-2 read stride 130 -> 2-way banks
    const int t = threadIdx.x;
    const int j0 = blockIdx.x * 64;
    #pragma unroll
    for (int k = 0; k < 32; ++k) {
        const int idx = k * 256 + t;
        const int j = idx >> 7;
        const int c = idx & 127;
        ls[j][c] = wh[(size_t)(j0 + j) * OUTD + c];
    }
    __syncthreads();
    #pragma unroll
    for (int k = 0; k < 32; ++k) {
        const int idx = k * 256 + t;
        const int c = idx >> 6;       // constant per wave -> 128B contiguous store
        const int j = idx & 63;
        whT[(size_t)c * N + j0 + j] = f2bf(ls[j][c]);
    }
}

// ---------------- Kernel B: flash GAT with MFMA PV (ROUND-15 CHAMPION, reverted) ----------------
// r16 (3 blocks/CU, 1-deep) = 101.5 us; r17 (direct reg loads) = 99.3 us; this
// structure = 91.3 us. The 2-deep E[3] pipeline at 2 blocks/CU with
// global_load_lds staging is the measured optimum of the neighborhood.
// Shape: BI=16 (MFMA M), BJ=64, NCH=2 j-chunks -> grid 512, 2 blocks/CU.
// Fragments: A = P[16 rows][64 k] bf16 in LDS, stride 72 (144B: 16B-aligned
//   b128 A-reads, 2-way banks = free). lane: row=L&15, k=(L>>4)*8+q [m89 layout].
// B = whT[col][k] bf16 from GLOBAL (L2, 1 MB) straight to regs: lane col=L&15,
//   8 contig k. Wave w owns cols [32w,32w+32); D: col=L&15, row=(L>>4)*4+reg.
// Sync skeleton: [A] B-frags+sj(st+1)->regs, sched_barrier; [C] scores(st)
// E[b0]->P[pb] (p=exp(s) direct, r13-validated); [D] STAGE(st+2);
// [E] lgkmcnt(0)+barrier; [F] MFMA; [G] barrier. Counted-FIFO property: MFMA's
// wait retires stage(st+1) only; stage(st+2) stays in flight (T4).
// Raw partials + per-chunk l; merge divides. VGPR ~90 under (256,1) cap 256.
#define BI 16
#define BJ 64
#define NCH 2
#define CHJ (N / NCH)          // 2048
#define NSUB (CHJ / BJ)        // 32
#define PPAD 72                // P row stride in bf16 (144 B)
#define EFLOATS (BI * BJ * 5)  // 5120 floats = 20 KB per buffer

__device__ __forceinline__ void gload_lds16(const void* g, void* l) {
    __builtin_amdgcn_global_load_lds(
        (const __attribute__((address_space(1))) unsigned int*)(g),
        (__attribute__((address_space(3))) unsigned int*)(l),
        16, 0, 0);
}

__global__ __launch_bounds__(256, 1) void gat_mfma(const float* __restrict__ edges,
                                                   const unsigned short* __restrict__ whT,
                                                   const float* __restrict__ s_iv,
                                                   const float* __restrict__ s_jv,
                                                   const float* __restrict__ a,
                                                   float* __restrict__ part,
                                                   float* __restrict__ lout) {
    __shared__ float E[3][EFLOATS];              // 60 KB
    __shared__ unsigned short P[2][BI * PPAD];   // 4.6 KB

    const int t = threadIdx.x;
    const int ib = blockIdx.x & 255;
    const int ch = blockIdx.x >> 8;
    const int i0 = ib * BI;
    const int jbase = ch * CHJ;
    const int w = t >> 6;
    const int s = t & 63;
    const int lhi = s >> 4;    // lane>>4 within wave (0..3)
    const int llo = s & 15;    // lane&15

    const float ae0 = a[OUTD + 0], ae1 = a[OUTD + 1], ae2 = a[OUTD + 2],
                ae3 = a[OUTD + 3], ae4 = a[OUTD + 4];
    float si[4];
    #pragma unroll
    for (int rr = 0; rr < 4; ++rr) si[rr] = s_iv[i0 + 4 * w + rr];

    // Stage sources: float4 f = k*256+t of the 1280-float4 (16x64x5) tile;
    // row = f/80, rem = f%80 are subtile-invariant; jbase folded into base ptr.
    const char* g0; const char* g1; const char* g2; const char* g3; const char* g4;
    {
        const char* eb = (const char*)edges + (size_t)jbase * 20;
        #define MKG(K, VAR)                                                    \
        {   const int f = K * 256 + t;                                         \
            const int row = f / 80;                                            \
            const int rem = f - row * 80;                                      \
            VAR = eb + (size_t)(i0 + row) * (N * 20) + (size_t)rem * 16; }
        MKG(0, g0) MKG(1, g1) MKG(2, g2) MKG(3, g3) MKG(4, g4)
        #undef MKG
    }
    #define STAGE(BB, ST)                                                      \
    {   const size_t jo = (size_t)(ST) * (BJ * 20);                            \
        gload_lds16(g0 + jo, &E[BB][(0 * 256 + t) * 4]);                       \
        gload_lds16(g1 + jo, &E[BB][(1 * 256 + t) * 4]);                       \
        gload_lds16(g2 + jo, &E[BB][(2 * 256 + t) * 4]);                       \
        gload_lds16(g3 + jo, &E[BB][(3 * 256 + t) * 4]);                       \
        gload_lds16(g4 + jo, &E[BB][(4 * 256 + t) * 4]); }

    f32x4 acc0 = {0.f, 0.f, 0.f, 0.f};
    f32x4 acc1 = {0.f, 0.f, 0.f, 0.f};
    float lac[4] = {0.f, 0.f, 0.f, 0.f};

    // B-operand row pointers: tile0 col = 32w+llo, tile1 col = 32w+16+llo
    const unsigned short* wt0 = whT + (size_t)(w * 32 + llo) * N;
    const unsigned short* wt1 = wt0 + (size_t)16 * N;

    // ---- prologue: sj(0), stage(0), stage(1); retire sj+stage0 only ----
    float sj = s_jv[jbase + s];
    STAGE(0, 0)
    STAGE(1, 1)
    asm volatile("s_waitcnt vmcnt(5)" ::: "memory");
    __builtin_amdgcn_s_barrier();

    int b0 = 0, b1 = 1, b2 = 2;
    for (int st = 0; st < NSUB; ++st) {
        const int pb = st & 1;
        const int jb = jbase + st * BJ;   // absolute j of subtile start

        // ---- [A] B-fragments(st) + sj(st+1) -> regs, BEFORE this iter's stage ----
        const int kof = jb + lhi * 8;
        const bf16x8 B00 = *(const bf16x8*)(wt0 + kof);
        const bf16x8 B01 = *(const bf16x8*)(wt0 + kof + 32);
        const bf16x8 B10 = *(const bf16x8*)(wt1 + kof);
        const bf16x8 B11 = *(const bf16x8*)(wt1 + kof + 32);
        float sj_nx = 0.f;
        if (st + 1 < NSUB) sj_nx = s_jv[jb + BJ + s];
        __builtin_amdgcn_sched_barrier(0);

        // ---- [C] scores(st): p = exp(s) direct (r13-validated), bf16 -> P ----
        {
            const float* Eb = &E[b0][0];
            #pragma unroll
            for (int rr = 0; rr < 4; ++rr) {
                const int row = 4 * w + rr;
                const int e = row * 320 + s * 5;
                float d = Eb[e + 4] * ae4;
                d = fmaf(Eb[e + 0], ae0, d);
                d = fmaf(Eb[e + 1], ae1, d);
                d = fmaf(Eb[e + 2], ae2, d);
                d = fmaf(Eb[e + 3], ae3, d);
                float v = si[rr] + d + sj;
                v = fmaxf(v, 0.2f * v);             // leaky relu before mask
                if (jb + s == i0 + row) v = NEGV;   // diag -> exp -> 0
                const float p = __expf(v);
                lac[rr] += p;
                P[pb][row * PPAD + s] = f2bf(p);
            }
        }

        // ---- [D] stage st+2 into E[b2] ----
        if (st + 2 < NSUB) {
            STAGE(b2, st + 2)
        }

        // ---- [E] LDS-only barrier: P visible; stages stay in flight ----
        asm volatile("s_waitcnt lgkmcnt(0)" ::: "memory");
        __builtin_amdgcn_s_barrier();
        asm volatile("" ::: "memory");

        // ---- [F] MFMA PV: A from P (b128 x2), B from regs ----
        {
            const unsigned short* Pb = &P[pb][0];
            const bf16x8 A0 = *(const bf16x8*)(Pb + llo * PPAD + lhi * 8);
            const bf16x8 A1 = *(const bf16x8*)(Pb + llo * PPAD + 32 + lhi * 8);
            acc0 = __builtin_amdgcn_mfma_f32_16x16x32_bf16(A0, B00, acc0, 0, 0, 0);
            acc1 = __builtin_amdgcn_mfma_f32_16x16x32_bf16(A0, B10, acc1, 0, 0, 0);
            acc0 = __builtin_amdgcn_mfma_f32_16x16x32_bf16(A1, B01, acc0, 0, 0, 0);
            acc1 = __builtin_amdgcn_mfma_f32_16x16x32_bf16(A1, B11, acc1, 0, 0, 0);
        }

        // ---- [G] rotate; plain barrier (publishes stage retirement; NO drain) ----
        sj = sj_nx;
        __builtin_amdgcn_s_barrier();
        const int tb = b0; b0 = b1; b1 = b2; b2 = tb;
    }

    // ---- epilogue: reduce l once; write raw partials (merge normalizes) ----
    #pragma unroll
    for (int rr = 0; rr < 4; ++rr) {
        #pragma unroll
        for (int off = 32; off >= 1; off >>= 1)
            lac[rr] += __shfl_xor(lac[rr], off);
    }
    if (s == 0) {
        #pragma unroll
        for (int rr = 0; rr < 4; ++rr)
            lout[(size_t)ch * N + i0 + 4 * w + rr] = lac[rr];
    }
    #pragma unroll
    for (int reg = 0; reg < 4; ++reg) {
        const int row = lhi * 4 + reg;          // D row = (lane>>4)*4 + reg
        float* pr = part + ((size_t)ch * N + (i0 + row)) * OUTD + w * 32 + llo;
        pr[0]  = acc0[reg];
        pr[16] = acc1[reg];
    }
}

// ---------------- Kernel C: merge the 2 chunk partials ----------------
__global__ __launch_bounds__(256) void gat_merge(const float* __restrict__ part,
                                                 const float* __restrict__ lout,
                                                 float* __restrict__ out) {
    const int idx = blockIdx.x * 256 + threadIdx.x;   // over N*OUTD
    const int i = idx >> 7;
    const float L = lout[i] + lout[N + i];
    out[idx] = (part[idx] + part[(size_t)N * OUTD + idx]) / L;
}

extern "C" void kernel_launch(void* const* d_in, const int* in_sizes, int n_in,
                              void* d_out, int out_size, void* d_ws, size_t ws_size,
                              hipStream_t stream) {
    // inputs: 0=ids(int, unused), 1=lstm_out, 2=edges_list, 3=W, 4=a, 5=first(unused)
    const float* lstm_out = (const float*)d_in[1];
    const float* edges    = (const float*)d_in[2];
    const float* W        = (const float*)d_in[3];
    const float* a        = (const float*)d_in[4];
    float* out = (float*)d_out;

    float* wh   = (float*)d_ws;                        // 4096*128 f32
    float* s_i  = wh + (size_t)N * OUTD;               // 4096
    float* s_j  = s_i + N;                             // 4096
    float* lout = s_j + N;                             // 2*4096
    float* part = lout + (size_t)NCH * N;              // 2*4096*128 f32 (4 MB)
    unsigned short* whT = (unsigned short*)(part + (size_t)NCH * N * OUTD); // 128*4096 bf16 (1 MB)

    wh_kernel<<<N / 8, 256, 0, stream>>>(lstm_out, W, wh);
    sij_kernel<<<N, 128, 0, stream>>>(wh, a, s_i, s_j);
    whT_kernel<<<N / 64, 256, 0, stream>>>(wh, whT);
    gat_mfma<<<256 * NCH, 256, 0, stream>>>(edges, whT, s_i, s_j, a, part, lout);
    gat_merge<<<(N * OUTD) / 256, 256, 0, stream>>>(part, lout, out);
}